// Round 1
// baseline (907.669 us; speedup 1.0000x reference)
//
#include <hip/hip_runtime.h>
#include <hip/hip_bf16.h>

#define Bb 8
#define Ss 512
#define Nn 128
#define DIN 256
#define DHID 128
#define DOUT 64

typedef __attribute__((ext_vector_type(8))) __bf16 bf16x8;
typedef __attribute__((ext_vector_type(4))) float f32x4;

__device__ __forceinline__ unsigned short f2bf(float f) {
  unsigned u = __float_as_uint(f);
  u += 0x7fffu + ((u >> 16) & 1u);
  return (unsigned short)(u >> 16);
}
__device__ __forceinline__ float bf2f(unsigned short h) {
  return __uint_as_float(((unsigned)h) << 16);
}

// ---- prep: split W1 (128x256 fp32) into bf16 hi + lo residual ----
__global__ void prep_w1(const float* __restrict__ W1,
                        unsigned short* __restrict__ w1h,
                        unsigned short* __restrict__ w1l) {
  int i = blockIdx.x * 256 + threadIdx.x;   // grid 128 -> 32768 = exact
  float f = W1[i];
  unsigned short h = f2bf(f);
  w1h[i] = h;
  w1l[i] = f2bf(f - bf2f(h));
}

// ---- kernel A: scores[m] = mask * relu(X[m]·W1^T + b1)·w_len ------------
// M = 524288 rows; 512 threads = 8 waves; wave w owns hid-cols [16w,16w+16)
// 32-row M-tiles; LDS x tile stores hi (k 0..255) and lo (k 256..511), row
// stride 520 shorts (pad 8 -> bank rotation 4, 2-way conflicts only = free).
__global__ __launch_bounds__(512) void scores_kernel(
    const float* __restrict__ x, const unsigned short* __restrict__ w1h,
    const unsigned short* __restrict__ w1l, const float* __restrict__ b1,
    const float* __restrict__ wlen, const int* __restrict__ seqlen,
    float* __restrict__ scores) {
  __shared__ unsigned short xs[32 * 520];
  __shared__ float part[8][32];
  const int t = threadIdx.x;
  const int lane = t & 63;
  const int w = t >> 6;        // 0..7
  const int quad = lane >> 4;  // 0..3
  const int l15 = lane & 15;
  const int col = w * 16 + l15;  // hid column 0..127

  // B fragments (hi+lo) for this lane's column, all 8 k-steps: 64 VGPRs
  bf16x8 bh[8], bl[8];
#pragma unroll
  for (int ks = 0; ks < 8; ++ks) {
    int off = col * 256 + ks * 32 + quad * 8;
    bh[ks] = *(const bf16x8*)(w1h + off);
    bl[ks] = *(const bf16x8*)(w1l + off);
  }
  const float b1c = b1[col];
  const float wlc = wlen[col];

  for (int it = 0; it < 8; ++it) {
    const long tile = (long)blockIdx.x * 8 + it;  // 2048 blocks * 8 = 16384
    const long m0 = tile * 32;
    // stage 32 rows x 256 k (fp32 -> bf16 hi/lo). 2048 float4s, 4/thread.
    const float4* x4 = (const float4*)(x + m0 * DIN);
#pragma unroll
    for (int i = 0; i < 4; ++i) {
      int flat = t + 512 * i;          // == row*64 + c4
      int row = flat >> 6, c4 = flat & 63;
      float4 v = x4[flat];
      unsigned short h0 = f2bf(v.x), h1 = f2bf(v.y), h2 = f2bf(v.z), h3 = f2bf(v.w);
      unsigned short g0 = f2bf(v.x - bf2f(h0)), g1 = f2bf(v.y - bf2f(h1));
      unsigned short g2 = f2bf(v.z - bf2f(h2)), g3 = f2bf(v.w - bf2f(h3));
      uint2 ph, pl;
      ph.x = (unsigned)h0 | ((unsigned)h1 << 16);
      ph.y = (unsigned)h2 | ((unsigned)h3 << 16);
      pl.x = (unsigned)g0 | ((unsigned)g1 << 16);
      pl.y = (unsigned)g2 | ((unsigned)g3 << 16);
      *(uint2*)&xs[row * 520 + c4 * 4] = ph;
      *(uint2*)&xs[row * 520 + 256 + c4 * 4] = pl;
    }
    __syncthreads();

#pragma unroll
    for (int mt = 0; mt < 2; ++mt) {
      f32x4 acc = {0.f, 0.f, 0.f, 0.f};
      const int rbase = (mt * 16 + l15) * 520;
#pragma unroll
      for (int ks = 0; ks < 8; ++ks) {
        const int k0 = ks * 32 + quad * 8;
        bf16x8 ah = *(const bf16x8*)&xs[rbase + k0];
        bf16x8 al = *(const bf16x8*)&xs[rbase + 256 + k0];
        acc = __builtin_amdgcn_mfma_f32_16x16x32_bf16(ah, bh[ks], acc, 0, 0, 0);
        acc = __builtin_amdgcn_mfma_f32_16x16x32_bf16(al, bh[ks], acc, 0, 0, 0);
        acc = __builtin_amdgcn_mfma_f32_16x16x32_bf16(ah, bl[ks], acc, 0, 0, 0);
      }
      // epilogue: relu(+b1)*w_len, reduce over this wave's 16 cols
      float p0 = fmaxf(acc[0] + b1c, 0.f) * wlc;
      float p1 = fmaxf(acc[1] + b1c, 0.f) * wlc;
      float p2 = fmaxf(acc[2] + b1c, 0.f) * wlc;
      float p3 = fmaxf(acc[3] + b1c, 0.f) * wlc;
#pragma unroll
      for (int off = 1; off < 16; off <<= 1) {
        p0 += __shfl_xor(p0, off);
        p1 += __shfl_xor(p1, off);
        p2 += __shfl_xor(p2, off);
        p3 += __shfl_xor(p3, off);
      }
      if (l15 < 4) {
        float pv = (l15 == 0) ? p0 : (l15 == 1) ? p1 : (l15 == 2) ? p2 : p3;
        part[w][mt * 16 + quad * 4 + l15] = pv;
      }
    }
    __syncthreads();
    if (t < 32) {
      float v = 0.f;
#pragma unroll
      for (int ww = 0; ww < 8; ++ww) v += part[ww][t];
      long m = m0 + t;
      int b = (int)(m >> 16);          // S*N = 65536
      int s = ((int)m >> 7) & 511;
      float mask = (s < seqlen[b]) ? 1.0f : -10.0f;
      scores[m] = v * mask;
    }
    // next staging write is gated by the post-stage __syncthreads
  }
}

// ---- kernel B: softmax over s for each (b,n) ----
__global__ void softmax_kernel(const float* __restrict__ scores,
                               float* __restrict__ attn) {
  const int bi = blockIdx.x;           // 1024 = b*128+n
  const int b = bi >> 7, n = bi & 127;
  const int t = threadIdx.x;           // 256
  const float* sp = scores + (long)b * Ss * Nn + n;
  float v0 = sp[(long)t * Nn];
  float v1 = sp[(long)(t + 256) * Nn];
  __shared__ float red[256];
  red[t] = fmaxf(v0, v1);
  __syncthreads();
  for (int o = 128; o > 0; o >>= 1) {
    if (t < o) red[t] = fmaxf(red[t], red[t + o]);
    __syncthreads();
  }
  const float mx = red[0];
  __syncthreads();
  float e0 = expf(v0 - mx), e1 = expf(v1 - mx);
  red[t] = e0 + e1;
  __syncthreads();
  for (int o = 128; o > 0; o >>= 1) {
    if (t < o) red[t] += red[t + o];
    __syncthreads();
  }
  const float inv = 1.0f / red[0];
  float* ap = attn + (long)b * Ss * Nn + n;
  ap[(long)t * Nn] = e0 * inv;
  ap[(long)(t + 256) * Nn] = e1 * inv;
}

// ---- kernel C: pooled[b,n,:] = sum_s attn[b,s,n] * x[b,s,n,:] ----
__global__ __launch_bounds__(512) void pool_kernel(
    const float* __restrict__ x, const float* __restrict__ attn,
    float* __restrict__ pooled) {
  const int bi = blockIdx.x;           // 1024 = b*128+n
  const int b = bi >> 7, n = bi & 127;
  const int t = threadIdx.x;           // 512
  const int sl = t >> 6, d4 = t & 63;  // 8-way s-split, float4 over D=256
  const float4* xb = (const float4*)x;
  float4 acc = {0.f, 0.f, 0.f, 0.f};
#pragma unroll 4
  for (int s = sl; s < Ss; s += 8) {
    const long row = (long)(b * Ss + s) * Nn + n;
    float a = attn[row];
    float4 v = xb[row * 64 + d4];
    acc.x += a * v.x; acc.y += a * v.y; acc.z += a * v.z; acc.w += a * v.w;
  }
  __shared__ float4 red[8][64];
  red[sl][d4] = acc;
  __syncthreads();
  if (sl == 0) {
    float4 r = red[0][d4];
#pragma unroll
    for (int ww = 1; ww < 8; ++ww) {
      float4 q = red[ww][d4];
      r.x += q.x; r.y += q.y; r.z += q.z; r.w += q.w;
    }
    ((float4*)pooled)[(long)bi * 64 + d4] = r;
  }
}

// ---- kernel D: g[b,n,:] = (sigmoid(p·Wa^T+ba) * tanh(p·We^T+be))·Wf^T + bf
__global__ void readout_kernel(const float* __restrict__ pooled,
                               const float* __restrict__ Wa, const float* __restrict__ ba,
                               const float* __restrict__ We, const float* __restrict__ be,
                               const float* __restrict__ Wf, const float* __restrict__ bfv,
                               float* __restrict__ g) {
  const int bi = blockIdx.x;  // 1024 = b*128+n
  const int t = threadIdx.x;  // 256
  __shared__ __align__(16) float p[256];
  __shared__ __align__(16) float tv[256];
  p[t] = pooled[(long)bi * 256 + t];
  __syncthreads();
  float da = ba[t], de = be[t];
  const float4* pa = (const float4*)p;
  const float4* wa = (const float4*)(Wa + (long)t * 256);
  const float4* we = (const float4*)(We + (long)t * 256);
#pragma unroll 4
  for (int i = 0; i < 64; ++i) {
    float4 pv = pa[i], av = wa[i], ev = we[i];
    da += pv.x * av.x + pv.y * av.y + pv.z * av.z + pv.w * av.w;
    de += pv.x * ev.x + pv.y * ev.y + pv.z * ev.z + pv.w * ev.w;
  }
  float sig = 1.0f / (1.0f + expf(-da));
  float th = tanhf(de);
  tv[t] = sig * th;
  __syncthreads();
  if (t < 64) {
    float go = bfv[t];
    const float4* wf = (const float4*)(Wf + (long)t * 256);
    const float4* tp = (const float4*)tv;
#pragma unroll 4
    for (int i = 0; i < 64; ++i) {
      float4 a = tp[i], q = wf[i];
      go += a.x * q.x + a.y * q.y + a.z * q.z + a.w * q.w;
    }
    g[(long)bi * 64 + t] = go;
  }
}

// ---- kernel E: out[b,:] = sum_n g / 128 + max_n g ----
__global__ void finalize_kernel(const float* __restrict__ g, float* __restrict__ out) {
  const int b = blockIdx.x;   // 8
  const int o = threadIdx.x;  // 64
  float sum = 0.f, mx = -INFINITY;
  for (int n = 0; n < Nn; ++n) {
    float v = g[((long)b * Nn + n) * DOUT + o];
    sum += v;
    mx = fmaxf(mx, v);
  }
  out[b * DOUT + o] = sum * (1.0f / 128.0f) + mx;
}

extern "C" void kernel_launch(void* const* d_in, const int* in_sizes, int n_in,
                              void* d_out, int out_size, void* d_ws, size_t ws_size,
                              hipStream_t stream) {
  const float* x   = (const float*)d_in[0];
  const int* seql  = (const int*)d_in[1];
  const float* W1  = (const float*)d_in[2];
  const float* b1  = (const float*)d_in[3];
  const float* wl  = (const float*)d_in[4];
  const float* Wa  = (const float*)d_in[5];
  const float* ba  = (const float*)d_in[6];
  const float* We  = (const float*)d_in[7];
  const float* be  = (const float*)d_in[8];
  const float* Wf  = (const float*)d_in[9];
  const float* bfv = (const float*)d_in[10];
  float* out = (float*)d_out;

  char* ws = (char*)d_ws;
  unsigned short* w1h = (unsigned short*)(ws);                 // 64 KB
  unsigned short* w1l = (unsigned short*)(ws + 65536);         // 64 KB
  float* scores = (float*)(ws + 131072);                       // 2 MB
  float* attn   = (float*)(ws + 131072 + 2097152);             // 2 MB
  float* pooled = (float*)(ws + 131072 + 2 * 2097152);         // 1 MB
  float* g      = (float*)(ws + 131072 + 2 * 2097152 + 1048576); // 256 KB

  prep_w1<<<128, 256, 0, stream>>>(W1, w1h, w1l);
  scores_kernel<<<2048, 512, 0, stream>>>(x, w1h, w1l, b1, wl, seql, scores);
  softmax_kernel<<<1024, 256, 0, stream>>>(scores, attn);
  pool_kernel<<<1024, 512, 0, stream>>>(x, attn, pooled);
  readout_kernel<<<1024, 256, 0, stream>>>(pooled, Wa, ba, We, be, Wf, bfv, g);
  finalize_kernel<<<8, 64, 0, stream>>>(g, out);
}

// Round 2
// 841.368 us; speedup vs baseline: 1.0788x; 1.0788x over previous
//
#include <hip/hip_runtime.h>
#include <hip/hip_bf16.h>

#define Bb 8
#define Ss 512
#define Nn 128
#define DIN 256
#define DHID 128
#define DOUT 64
#define TN 16   // n rows per tile / block
#define TS 32   // s values per block (16 chunks)

typedef __attribute__((ext_vector_type(8))) __bf16 bf16x8;
typedef __attribute__((ext_vector_type(4))) float f32x4;

__device__ __forceinline__ unsigned short f2bf(float f) {
  unsigned u = __float_as_uint(f);
  u += 0x7fffu + ((u >> 16) & 1u);
  return (unsigned short)(u >> 16);
}
__device__ __forceinline__ float bf2f(unsigned short h) {
  return __uint_as_float(((unsigned)h) << 16);
}

// ---- prep: split W1 (128x256 fp32) into bf16 hi + lo residual ----
__global__ void prep_w1(const float* __restrict__ W1,
                        unsigned short* __restrict__ w1h,
                        unsigned short* __restrict__ w1l) {
  int i = blockIdx.x * 256 + threadIdx.x;   // grid 128 -> 32768 = exact
  float f = W1[i];
  unsigned short h = f2bf(f);
  w1h[i] = h;
  w1l[i] = f2bf(f - bf2f(h));
}

// ---- fused flash kernel: scores + online softmax + weighted pooling ----
// grid 1024 = b(8) x ng(8) x sc(16); block 512 = 8 waves.
// Per s: stage x[b,s,ng*16:+16,0:256] as bf16 hi/lo in LDS; MFMA 3-product
// scores (wave w owns hid cols 16w..16w+15); cross-wave reduce; online
// softmax (state in regs of threads 0..15); pooled acc 8 floats/thread.
__global__ __launch_bounds__(512, 4) void flash_kernel(
    const float* __restrict__ x, const unsigned short* __restrict__ w1h,
    const unsigned short* __restrict__ w1l, const float* __restrict__ b1,
    const float* __restrict__ wlen, const int* __restrict__ seqlen,
    float* __restrict__ pml, float* __restrict__ pp) {
  __shared__ unsigned short xs[TN * 520];   // row n: hi at [0,256), lo at [256,512), pad 8
  __shared__ float part[8][TN];
  __shared__ float alpha_s[TN], ew_s[TN];
  const int t = threadIdx.x;
  const int lane = t & 63;
  const int w = t >> 6;        // wave 0..7
  const int quad = lane >> 4;  // 0..3
  const int l15 = lane & 15;
  const int col = w * 16 + l15;  // hid col 0..127

  const int bi = blockIdx.x;
  const int b = bi >> 7;
  const int ng = (bi >> 4) & 7;
  const int sc = bi & 15;
  const int slen = seqlen[b];

  bf16x8 bh[8], bl[8];
#pragma unroll
  for (int ks = 0; ks < 8; ++ks) {
    int off = col * 256 + ks * 32 + quad * 8;
    bh[ks] = *(const bf16x8*)(w1h + off);
    bl[ks] = *(const bf16x8*)(w1l + off);
  }
  const float b1c = b1[col];
  const float wlc = wlen[col];

  float m_st = -INFINITY, l_st = 0.f;   // live in threads t<16 (n = t)
  float acc[8];
#pragma unroll
  for (int j = 0; j < 8; ++j) acc[j] = 0.f;
  const int n_l = t >> 5;        // pooled ownership: n row 0..15
  const int d0 = (t & 31) * 8;   // 8 d per thread

  for (int i = 0; i < TS; ++i) {
    const int s = sc * TS + i;
    // stage 16 rows x 256 d: 1024 float4, 2 per thread
    const float4* x4 = (const float4*)(x + (((long)b * Ss + s) * Nn + ng * TN) * DIN);
#pragma unroll
    for (int ii = 0; ii < 2; ++ii) {
      int flat = t + 512 * ii;
      int row = flat >> 6, c4 = flat & 63;
      float4 v = x4[flat];
      unsigned short h0 = f2bf(v.x), h1 = f2bf(v.y), h2 = f2bf(v.z), h3 = f2bf(v.w);
      unsigned short g0 = f2bf(v.x - bf2f(h0)), g1 = f2bf(v.y - bf2f(h1));
      unsigned short g2 = f2bf(v.z - bf2f(h2)), g3 = f2bf(v.w - bf2f(h3));
      uint2 ph, pl;
      ph.x = (unsigned)h0 | ((unsigned)h1 << 16);
      ph.y = (unsigned)h2 | ((unsigned)h3 << 16);
      pl.x = (unsigned)g0 | ((unsigned)g1 << 16);
      pl.y = (unsigned)g2 | ((unsigned)g3 << 16);
      *(uint2*)&xs[row * 520 + c4 * 4] = ph;
      *(uint2*)&xs[row * 520 + 256 + c4 * 4] = pl;
    }
    __syncthreads();

    // scores for the 16 n-rows of this s
    f32x4 sacc = {0.f, 0.f, 0.f, 0.f};
#pragma unroll
    for (int ks = 0; ks < 8; ++ks) {
      const int k0 = ks * 32 + quad * 8;
      bf16x8 ah = *(const bf16x8*)&xs[l15 * 520 + k0];
      bf16x8 al = *(const bf16x8*)&xs[l15 * 520 + 256 + k0];
      sacc = __builtin_amdgcn_mfma_f32_16x16x32_bf16(ah, bh[ks], sacc, 0, 0, 0);
      sacc = __builtin_amdgcn_mfma_f32_16x16x32_bf16(al, bh[ks], sacc, 0, 0, 0);
      sacc = __builtin_amdgcn_mfma_f32_16x16x32_bf16(ah, bl[ks], sacc, 0, 0, 0);
    }
    float p0 = fmaxf(sacc[0] + b1c, 0.f) * wlc;
    float p1 = fmaxf(sacc[1] + b1c, 0.f) * wlc;
    float p2 = fmaxf(sacc[2] + b1c, 0.f) * wlc;
    float p3 = fmaxf(sacc[3] + b1c, 0.f) * wlc;
#pragma unroll
    for (int off = 1; off < 16; off <<= 1) {
      p0 += __shfl_xor(p0, off);
      p1 += __shfl_xor(p1, off);
      p2 += __shfl_xor(p2, off);
      p3 += __shfl_xor(p3, off);
    }
    if (l15 < 4) {
      float pv = (l15 == 0) ? p0 : (l15 == 1) ? p1 : (l15 == 2) ? p2 : p3;
      part[w][quad * 4 + l15] = pv;
    }
    __syncthreads();

    // online softmax update (threads 0..15 own n rows)
    if (t < TN) {
      float raw = 0.f;
#pragma unroll
      for (int ww = 0; ww < 8; ++ww) raw += part[ww][t];
      float mask = (s < slen) ? 1.0f : -10.0f;
      float scv = raw * mask;
      float m_new = fmaxf(m_st, scv);
      float a = expf(m_st - m_new);
      float e = expf(scv - m_new);
      l_st = l_st * a + e;
      m_st = m_new;
      alpha_s[t] = a;
      ew_s[t] = e;
    }
    __syncthreads();

    // pooled accumulate: acc = acc*alpha + e * x  (x = hi + lo)
    {
      const float a = alpha_s[n_l];
      const float e = ew_s[n_l];
      bf16x8 xh = *(const bf16x8*)&xs[n_l * 520 + d0];
      bf16x8 xl = *(const bf16x8*)&xs[n_l * 520 + 256 + d0];
#pragma unroll
      for (int j = 0; j < 8; ++j) {
        float xv = (float)xh[j] + (float)xl[j];
        acc[j] = fmaf(acc[j], a, e * xv);
      }
    }
    __syncthreads();  // xs reused next iteration
  }

  // write partials
  {
    float* dst = pp + ((long)bi * TN + n_l) * 256 + d0;
    float4 v0 = {acc[0], acc[1], acc[2], acc[3]};
    float4 v1 = {acc[4], acc[5], acc[6], acc[7]};
    *(float4*)dst = v0;
    *(float4*)(dst + 4) = v1;
  }
  if (t < TN) {
    pml[bi * 32 + t] = m_st;
    pml[bi * 32 + 16 + t] = l_st;
  }
}

// ---- combine partials + gated readout ----
// grid 1024 = (b,n); block 256
__global__ __launch_bounds__(256) void combine_readout(
    const float* __restrict__ pml, const float* __restrict__ pp,
    const float* __restrict__ Wa, const float* __restrict__ ba,
    const float* __restrict__ We, const float* __restrict__ be,
    const float* __restrict__ Wf, const float* __restrict__ bfv,
    float* __restrict__ g) {
  const int bi = blockIdx.x;
  const int b = bi >> 7, n = bi & 127;
  const int ng = n >> 4, nl = n & 15;
  const int t = threadIdx.x;
  __shared__ float coef[16];
  __shared__ __align__(16) float p[256];
  __shared__ __align__(16) float tv[256];

  if (t < 16) {
    const int blk = b * 128 + ng * 16 + t;   // chunk t
    float m = pml[blk * 32 + nl];
    float l = pml[blk * 32 + 16 + nl];
    float M = m;
#pragma unroll
    for (int off = 1; off < 16; off <<= 1) M = fmaxf(M, __shfl_xor(M, off));
    float z = l * expf(m - M);
    float L = z;
#pragma unroll
    for (int off = 1; off < 16; off <<= 1) L += __shfl_xor(L, off);
    coef[t] = expf(m - M) / L;
  }
  __syncthreads();

  float accd = 0.f;
#pragma unroll
  for (int c = 0; c < 16; ++c) {
    accd += coef[c] * pp[((long)(b * 128 + ng * 16 + c) * TN + nl) * 256 + t];
  }
  p[t] = accd;
  __syncthreads();

  float da = ba[t], de = be[t];
  const float4* pa = (const float4*)p;
  const float4* wa = (const float4*)(Wa + (long)t * 256);
  const float4* we = (const float4*)(We + (long)t * 256);
#pragma unroll 4
  for (int i = 0; i < 64; ++i) {
    float4 pv = pa[i], av = wa[i], ev = we[i];
    da += pv.x * av.x + pv.y * av.y + pv.z * av.z + pv.w * av.w;
    de += pv.x * ev.x + pv.y * ev.y + pv.z * ev.z + pv.w * ev.w;
  }
  float sig = 1.0f / (1.0f + expf(-da));
  float th = tanhf(de);
  tv[t] = sig * th;
  __syncthreads();
  if (t < 64) {
    float go = bfv[t];
    const float4* wf = (const float4*)(Wf + (long)t * 256);
    const float4* tp = (const float4*)tv;
#pragma unroll 4
    for (int i = 0; i < 64; ++i) {
      float4 a = tp[i], q = wf[i];
      go += a.x * q.x + a.y * q.y + a.z * q.z + a.w * q.w;
    }
    g[(long)bi * 64 + t] = go;
  }
}

// ---- finalize: out[b,:] = sum_n g / 128 + max_n g ----
__global__ __launch_bounds__(512) void finalize_kernel(const float* __restrict__ g,
                                                       float* __restrict__ out) {
  const int b = blockIdx.x;   // 8
  const int t = threadIdx.x;  // 512
  const int o = t & 63, ns = t >> 6;
  float sum = 0.f, mx = -INFINITY;
  for (int n = ns; n < Nn; n += 8) {
    float v = g[((long)b * Nn + n) * DOUT + o];
    sum += v;
    mx = fmaxf(mx, v);
  }
  __shared__ float s1[8][64], s2[8][64];
  s1[ns][o] = sum;
  s2[ns][o] = mx;
  __syncthreads();
  if (ns == 0) {
#pragma unroll
    for (int ww = 1; ww < 8; ++ww) {
      sum += s1[ww][o];
      mx = fmaxf(mx, s2[ww][o]);
    }
    out[b * 64 + o] = sum * (1.0f / 128.0f) + mx;
  }
}

extern "C" void kernel_launch(void* const* d_in, const int* in_sizes, int n_in,
                              void* d_out, int out_size, void* d_ws, size_t ws_size,
                              hipStream_t stream) {
  const float* x   = (const float*)d_in[0];
  const int* seql  = (const int*)d_in[1];
  const float* W1  = (const float*)d_in[2];
  const float* b1  = (const float*)d_in[3];
  const float* wl  = (const float*)d_in[4];
  const float* Wa  = (const float*)d_in[5];
  const float* ba  = (const float*)d_in[6];
  const float* We  = (const float*)d_in[7];
  const float* be  = (const float*)d_in[8];
  const float* Wf  = (const float*)d_in[9];
  const float* bfv = (const float*)d_in[10];
  float* out = (float*)d_out;

  char* ws = (char*)d_ws;
  unsigned short* w1h = (unsigned short*)(ws);                   // 64 KB
  unsigned short* w1l = (unsigned short*)(ws + 65536);           // 64 KB
  float* pml = (float*)(ws + 131072);                            // 128 KB (1024*32)
  float* pp  = (float*)(ws + 262144);                            // 16 MB (1024*16*256)
  float* g   = (float*)(ws + 262144 + 16777216);                 // 256 KB

  prep_w1<<<128, 256, 0, stream>>>(W1, w1h, w1l);
  flash_kernel<<<1024, 512, 0, stream>>>(x, w1h, w1l, b1, wl, seql, pml, pp);
  combine_readout<<<1024, 256, 0, stream>>>(pml, pp, Wa, ba, We, be, Wf, bfv, g);
  finalize_kernel<<<8, 512, 0, stream>>>(g, out);
}